// Round 2
// baseline (89.969 us; speedup 1.0000x reference)
//
#include <hip/hip_runtime.h>
#include <math.h>

#define NSAMP 32
#define HW 512
#define PW 128
#define NPOOL (PW * PW)                 // 16384 pooled elements / sample
#define BLOCKS_PER_SAMPLE 64            // 16384 / 256
#define NBLOCKS (NSAMP * BLOCKS_PER_SAMPLE)  // 2048
#define NACC 14
#define PART_OFF_FLOATS 64              // partials start at byte 256 of ws

// acc layout: 0 bce(log2 units)  1 mask_cnt  2 intersection  3 label_sum
// 4 S_v 5 S_h 6 S_l 7 S_vv 8 S_hh 9 S_ll 10 S_vh 11 S_vl 12 S_hl 13 S_vhl

__device__ __forceinline__ float agload(const float* p) {
    // agent-scope load: bypasses non-coherent L1 / per-XCD L2 (sc0/sc1)
    return __hip_atomic_load(p, __ATOMIC_RELAXED, __HIP_MEMORY_SCOPE_AGENT);
}

__global__ __launch_bounds__(256) void covloss_fused(
    const float* __restrict__ logits, const float* __restrict__ labels,
    const float* __restrict__ v_att,  const float* __restrict__ h_att,
    float* __restrict__ out, unsigned int* __restrict__ ws)
{
    float* part = (float*)ws + PART_OFF_FLOATS;

    const int bid  = blockIdx.x;
    const int n    = bid / BLOCKS_PER_SAMPLE;
    const int pidx = (bid % BLOCKS_PER_SAMPLE) * 256 + threadIdx.x;
    const int pr   = pidx >> 7;          // pooled row 0..127
    const int pc   = pidx & 127;         // pooled col 0..127

    const float4* lg4 = (const float4*)(logits + (size_t)n * HW * HW + (size_t)(4 * pr) * HW) + pc;
    const float4* lb4 = (const float4*)(labels + (size_t)n * HW * HW + (size_t)(4 * pr) * HW) + pc;

    float bce2 = 0.f, inter = 0.f, lsum = 0.f;
    unsigned int cnt_u = 0;   // wave-uniform mask count via ballot/popcount

#pragma unroll
    for (int i = 0; i < 4; ++i) {
        const float4 p4 = lg4[i * (HW / 4)];
        const float4 y4 = lb4[i * (HW / 4)];
        const float pv[4] = {p4.x, p4.y, p4.z, p4.w};
        const float yv[4] = {y4.x, y4.y, y4.z, y4.w};
#pragma unroll
        for (int j = 0; j < 4; ++j) {
            const float p = pv[j], y = yv[j];
            bce2 = fmaf(y, __log2f(p), bce2);          // ln2 factored out to finalize
            bce2 = fmaf(1.f - y, __log2f(1.f - p), bce2);
            const bool m = p > 0.4f;
            cnt_u += (unsigned)__popcll(__ballot(m));  // scalar-pipe count
            inter += m ? y : 0.f;
            lsum  += y;                                 // also the 4x4 pool sum
        }
    }

    const float l = lsum * 0.0625f;       // 4x4 average pool value
    const float v = v_att[(size_t)n * NPOOL + pidx];
    const float h = h_att[(size_t)n * NPOOL + pidx];

    float vals[13] = { bce2, inter, lsum,
                       v, h, l,
                       v * v, h * h, l * l,
                       v * h, v * l, h * l, v * h * l };

#pragma unroll
    for (int k = 0; k < 13; ++k) {
        float x = vals[k];
#pragma unroll
        for (int off = 32; off > 0; off >>= 1) x += __shfl_down(x, off, 64);
        vals[k] = x;
    }

    __shared__ float sh[4][NACC];
    const int lane = threadIdx.x & 63, wv = threadIdx.x >> 6;
    if (lane == 0) {
        sh[wv][0] = vals[0];
        sh[wv][1] = (float)cnt_u;
        sh[wv][2] = vals[1];
        sh[wv][3] = vals[2];
#pragma unroll
        for (int k = 3; k < 13; ++k) sh[wv][k + 1] = vals[k];
    }
    __syncthreads();
    if (threadIdx.x < NACC) {
        part[(size_t)bid * NACC + threadIdx.x] =
            sh[0][threadIdx.x] + sh[1][threadIdx.x] + sh[2][threadIdx.x] + sh[3][threadIdx.x];
    }

    // ---- rendezvous: last block to arrive finalizes ----
    __shared__ int lastflag;
    __syncthreads();   // drains the part stores (vmcnt) before the release-atomic
    if (threadIdx.x == 0) {
        unsigned old = __hip_atomic_fetch_add(ws, 1u, __ATOMIC_ACQ_REL,
                                              __HIP_MEMORY_SCOPE_AGENT);
        lastflag = (old == NBLOCKS - 1);
    }
    __syncthreads();
    if (!lastflag) return;

    // ---- finalize (runs in exactly one block; fixed order -> deterministic) ----
    const int t = threadIdx.x, s = t >> 3, sub = t & 7;   // 8 threads / sample
    double a[NACC];
#pragma unroll
    for (int k = 0; k < NACC; ++k) a[k] = 0.0;
    for (int b = sub; b < BLOCKS_PER_SAMPLE; b += 8) {
        const float* p = part + (size_t)(s * BLOCKS_PER_SAMPLE + b) * NACC;
#pragma unroll
        for (int k = 0; k < NACC; ++k) a[k] += (double)agload(p + k);
    }
#pragma unroll
    for (int off = 4; off > 0; off >>= 1) {
#pragma unroll
        for (int k = 0; k < NACC; ++k) a[k] += __shfl_down(a[k], off, 8);
    }

    __shared__ double sb[NSAMP], sd[NSAMP], sc[NSAMP];
    if (sub == 0) {
        const double nn = (double)NPOOL;
        const double cvv = a[7] - a[4] * a[4] / nn;
        const double chh = a[8] - a[5] * a[5] / nn;
        const double cll = a[9] - a[6] * a[6] / nn;
        const double num = a[13]
            - (a[4] * a[12] + a[5] * a[11] + a[6] * a[10]) / nn
            + 2.0 * a[4] * a[5] * a[6] / (nn * nn);
        sc[s] = num / sqrt(cvv * chh * cll);
        sd[s] = 2.0 * (a[2] + 1.0) / (a[1] + a[3] + 1.0);
        sb[s] = a[0];
    }
    __syncthreads();
    if (t == 0) {
        double bces = 0.0, ds = 0.0, cs = 0.0;
#pragma unroll
        for (int i = 0; i < NSAMP; ++i) { bces += sb[i]; ds += sd[i]; cs += sc[i]; }
        const double bceloss = -(bces * M_LN2) / ((double)NSAMP * HW * HW);
        out[0] = (float)(0.2 * bceloss + 0.3 * (1.0 - ds / NSAMP) + 0.5 * (-cs / NSAMP));
    }
}

extern "C" void kernel_launch(void* const* d_in, const int* in_sizes, int n_in,
                              void* d_out, int out_size, void* d_ws, size_t ws_size,
                              hipStream_t stream) {
    const float* logits = (const float*)d_in[0];
    const float* labels = (const float*)d_in[1];
    const float* v_att  = (const float*)d_in[2];
    const float* h_att  = (const float*)d_in[3];
    float* out = (float*)d_out;
    unsigned int* ws = (unsigned int*)d_ws;

    hipMemsetAsync(d_ws, 0, 4, stream);   // zero the rendezvous counter (graph-legal)
    covloss_fused<<<NBLOCKS, 256, 0, stream>>>(logits, labels, v_att, h_att, out, ws);
}

// Round 3
// 27.475 us; speedup vs baseline: 3.2745x; 3.2745x over previous
//
#include <hip/hip_runtime.h>
#include <math.h>

#define NSAMP 32
#define HW 512
#define PW 128
#define NPOOL (PW * PW)                      // 16384 pooled elements / sample
#define BLOCKS_PER_SAMPLE 64                 // 16384 / 256
#define NBLOCKS (NSAMP * BLOCKS_PER_SAMPLE)  // 2048
#define NACC 14

// acc layout: 0 bce  1 mask_cnt  2 intersection  3 label_sum
// 4 S_v 5 S_h 6 S_l 7 S_vv 8 S_hh 9 S_ll 10 S_vh 11 S_vl 12 S_hl 13 S_vhl
// part is TRANSPOSED: part[k * NBLOCKS + bid]  -> finalize reads 64 contiguous floats

__global__ __launch_bounds__(256) void covloss_main(
    const float* __restrict__ logits, const float* __restrict__ labels,
    const float* __restrict__ v_att,  const float* __restrict__ h_att,
    float* __restrict__ part)
{
    const int bid  = blockIdx.x;
    const int n    = bid / BLOCKS_PER_SAMPLE;
    const int pidx = (bid % BLOCKS_PER_SAMPLE) * 256 + threadIdx.x;
    const int pr   = pidx >> 7;          // pooled row 0..127
    const int pc   = pidx & 127;         // pooled col 0..127

    const float4* lg4 = (const float4*)(logits + (size_t)n * HW * HW + (size_t)(4 * pr) * HW) + pc;
    const float4* lb4 = (const float4*)(labels + (size_t)n * HW * HW + (size_t)(4 * pr) * HW) + pc;

    float bce = 0.f, cnt = 0.f, inter = 0.f, lsum = 0.f;

#pragma unroll
    for (int i = 0; i < 4; ++i) {
        const float4 p4 = lg4[i * (HW / 4)];
        const float4 y4 = lb4[i * (HW / 4)];
        const float pv[4] = {p4.x, p4.y, p4.z, p4.w};
        const float yv[4] = {y4.x, y4.y, y4.z, y4.w};
#pragma unroll
        for (int j = 0; j < 4; ++j) {
            const float p = pv[j], y = yv[j];
            bce = fmaf(y, __logf(p), bce);
            bce = fmaf(1.f - y, __logf(1.f - p), bce);
            const bool m = p > 0.4f;
            cnt  += m ? 1.f : 0.f;
            inter += m ? y : 0.f;
            lsum += y;                       // also the 4x4 pool sum
        }
    }

    const float l = lsum * 0.0625f;          // 4x4 average pool value
    const float v = v_att[(size_t)n * NPOOL + pidx];
    const float h = h_att[(size_t)n * NPOOL + pidx];

    float vals[NACC] = { bce, cnt, inter, lsum,
                         v, h, l,
                         v * v, h * h, l * l,
                         v * h, v * l, h * l, v * h * l };

#pragma unroll
    for (int k = 0; k < NACC; ++k) {
        float x = vals[k];
#pragma unroll
        for (int off = 32; off > 0; off >>= 1) x += __shfl_down(x, off, 64);
        vals[k] = x;
    }

    __shared__ float sh[4][NACC];
    const int lane = threadIdx.x & 63, wv = threadIdx.x >> 6;
    if (lane == 0) {
#pragma unroll
        for (int k = 0; k < NACC; ++k) sh[wv][k] = vals[k];
    }
    __syncthreads();
    if (threadIdx.x < NACC) {
        part[(size_t)threadIdx.x * NBLOCKS + bid] =
            sh[0][threadIdx.x] + sh[1][threadIdx.x] + sh[2][threadIdx.x] + sh[3][threadIdx.x];
    }
}

__global__ __launch_bounds__(256) void covloss_finalize(
    const float* __restrict__ part, float* __restrict__ out)
{
    const int t = threadIdx.x;
    __shared__ double acc[NSAMP][NACC];      // 3.5 KB

    // 448 (sample, moment) pairs; each = sum of 64 contiguous floats
    for (int pair = t; pair < NSAMP * NACC; pair += 256) {
        const int s = pair / NACC, k = pair % NACC;
        const float4* p = (const float4*)(part + (size_t)k * NBLOCKS + s * BLOCKS_PER_SAMPLE);
        double a = 0.0;
#pragma unroll
        for (int i = 0; i < 16; ++i) {
            const float4 q = p[i];
            a += (double)q.x + (double)q.y + (double)q.z + (double)q.w;
        }
        acc[s][k] = a;
    }
    __syncthreads();

    __shared__ double sb[NSAMP], sd[NSAMP], sc[NSAMP];
    if (t < NSAMP) {
        const double* a = acc[t];
        const double nn = (double)NPOOL;
        const double cvv = a[7] - a[4] * a[4] / nn;
        const double chh = a[8] - a[5] * a[5] / nn;
        const double cll = a[9] - a[6] * a[6] / nn;
        const double num = a[13]
            - (a[4] * a[12] + a[5] * a[11] + a[6] * a[10]) / nn
            + 2.0 * a[4] * a[5] * a[6] / (nn * nn);
        sc[t] = num / sqrt(cvv * chh * cll);
        sd[t] = 2.0 * (a[2] + 1.0) / (a[1] + a[3] + 1.0);
        sb[t] = a[0];
    }
    __syncthreads();
    if (t == 0) {
        double bces = 0.0, ds = 0.0, cs = 0.0;
#pragma unroll
        for (int i = 0; i < NSAMP; ++i) { bces += sb[i]; ds += sd[i]; cs += sc[i]; }
        const double bceloss = -bces / ((double)NSAMP * HW * HW);
        out[0] = (float)(0.2 * bceloss + 0.3 * (1.0 - ds / NSAMP) + 0.5 * (-cs / NSAMP));
    }
}

extern "C" void kernel_launch(void* const* d_in, const int* in_sizes, int n_in,
                              void* d_out, int out_size, void* d_ws, size_t ws_size,
                              hipStream_t stream) {
    const float* logits = (const float*)d_in[0];
    const float* labels = (const float*)d_in[1];
    const float* v_att  = (const float*)d_in[2];
    const float* h_att  = (const float*)d_in[3];
    float* out  = (float*)d_out;
    float* part = (float*)d_ws;   // NACC * NBLOCKS floats = 112 KB

    covloss_main<<<NBLOCKS, 256, 0, stream>>>(logits, labels, v_att, h_att, part);
    covloss_finalize<<<1, 256, 0, stream>>>(part, out);
}

// Round 4
// 21.445 us; speedup vs baseline: 4.1954x; 1.2812x over previous
//
#include <hip/hip_runtime.h>
#include <math.h>

#define NSAMP 32
#define HW 512
#define PW 128
#define NPOOL (PW * PW)                 // 16384 pooled elements / sample
#define BPS 16                          // blocks per sample
#define NBLOCKS (NSAMP * BPS)           // 512
#define PPT 4                           // pooled patches per thread
#define NACC 14

// acc layout: 0 bce  1 mask_cnt  2 intersection  3 label_sum
// 4 S_v 5 S_h 6 S_l 7 S_vv 8 S_hh 9 S_ll 10 S_vh 11 S_vl 12 S_hl 13 S_vhl
// part is transposed: part[k * NBLOCKS + bid]

// full-wave (64 lane) sum via DPP on the VALU pipe; result valid in lane 63
__device__ __forceinline__ float wave_sum_dpp(float x) {
#define DPP_ADD(ctrl)                                                         \
    x += __int_as_float(__builtin_amdgcn_update_dpp(                          \
        0, __float_as_int(x), (ctrl), 0xf, 0xf, true));
    DPP_ADD(0x111)   // row_shr:1
    DPP_ADD(0x112)   // row_shr:2
    DPP_ADD(0x114)   // row_shr:4
    DPP_ADD(0x118)   // row_shr:8   -> lane 15 of each row16 holds row sum
    DPP_ADD(0x142)   // row_bcast:15 -> lane 31 = rows0-1, lane 63 = rows2-3(partial)
    DPP_ADD(0x143)   // row_bcast:31 -> lane 63 = full 64-lane sum
#undef DPP_ADD
    return x;
}

__global__ __launch_bounds__(256) void covloss_main(
    const float* __restrict__ logits, const float* __restrict__ labels,
    const float* __restrict__ v_att,  const float* __restrict__ h_att,
    float* __restrict__ part)
{
    const int bid   = blockIdx.x;
    const int n     = bid >> 4;              // sample
    const int local = bid & 15;              // block within sample

    const float* lg = logits + (size_t)n * HW * HW;
    const float* lb = labels + (size_t)n * HW * HW;
    const float* va = v_att + (size_t)n * NPOOL;
    const float* ha = h_att + (size_t)n * NPOOL;

    float bce = 0.f, cnt = 0.f, inter = 0.f, ysum = 0.f;
    float S_v = 0.f, S_h = 0.f, S_l = 0.f;
    float S_vv = 0.f, S_hh = 0.f, S_ll = 0.f;
    float S_vh = 0.f, S_vl = 0.f, S_hl = 0.f, S_vhl = 0.f;

#pragma unroll
    for (int p = 0; p < PPT; ++p) {
        const int pidx = local * (PPT * 256) + p * 256 + threadIdx.x;
        const int pr = pidx >> 7;            // pooled row 0..127
        const int pc = pidx & 127;           // pooled col 0..127
        const float4* lg4 = (const float4*)(lg + (size_t)(4 * pr) * HW) + pc;
        const float4* lb4 = (const float4*)(lb + (size_t)(4 * pr) * HW) + pc;

        float lsum = 0.f;
#pragma unroll
        for (int i = 0; i < 4; ++i) {
            const float4 p4 = lg4[i * (HW / 4)];
            const float4 y4 = lb4[i * (HW / 4)];
            const float pv[4] = {p4.x, p4.y, p4.z, p4.w};
            const float yv[4] = {y4.x, y4.y, y4.z, y4.w};
#pragma unroll
            for (int j = 0; j < 4; ++j) {
                const float pp = pv[j], y = yv[j];
                bce = fmaf(y, __logf(pp), bce);
                bce = fmaf(1.f - y, __logf(1.f - pp), bce);
                const bool m = pp > 0.4f;
                cnt   += m ? 1.f : 0.f;
                inter += m ? y : 0.f;
                lsum  += y;
            }
        }
        ysum += lsum;
        const float l = lsum * 0.0625f;      // 4x4 average pool value
        const float v = va[pidx];
        const float h = ha[pidx];
        S_v += v;          S_h += h;          S_l += l;
        S_vv = fmaf(v, v, S_vv);  S_hh = fmaf(h, h, S_hh);  S_ll = fmaf(l, l, S_ll);
        const float vh = v * h;
        S_vh += vh;        S_vl = fmaf(v, l, S_vl);  S_hl = fmaf(h, l, S_hl);
        S_vhl = fmaf(vh, l, S_vhl);
    }

    float vals[NACC] = { bce, cnt, inter, ysum,
                         S_v, S_h, S_l, S_vv, S_hh, S_ll,
                         S_vh, S_vl, S_hl, S_vhl };

#pragma unroll
    for (int k = 0; k < NACC; ++k) vals[k] = wave_sum_dpp(vals[k]);

    __shared__ float sh[4][NACC];
    const int lane = threadIdx.x & 63, wv = threadIdx.x >> 6;
    if (lane == 63) {
#pragma unroll
        for (int k = 0; k < NACC; ++k) sh[wv][k] = vals[k];
    }
    __syncthreads();
    if (threadIdx.x < NACC) {
        part[(size_t)threadIdx.x * NBLOCKS + bid] =
            sh[0][threadIdx.x] + sh[1][threadIdx.x] + sh[2][threadIdx.x] + sh[3][threadIdx.x];
    }
}

__global__ __launch_bounds__(256) void covloss_finalize(
    const float* __restrict__ part, float* __restrict__ out)
{
    const int t = threadIdx.x;
    __shared__ double acc[NSAMP][NACC];

    // 448 (sample, moment) pairs; each = sum of 16 contiguous floats
    for (int pair = t; pair < NSAMP * NACC; pair += 256) {
        const int s = pair / NACC, k = pair % NACC;
        const float4* p = (const float4*)(part + (size_t)k * NBLOCKS + s * BPS);
        double a = 0.0;
#pragma unroll
        for (int i = 0; i < 4; ++i) {
            const float4 q = p[i];
            a += (double)q.x + (double)q.y + (double)q.z + (double)q.w;
        }
        acc[s][k] = a;
    }
    __syncthreads();

    __shared__ double sb[NSAMP], sd[NSAMP], sc[NSAMP];
    if (t < NSAMP) {
        const double* a = acc[t];
        const double nn = (double)NPOOL;
        const double cvv = a[7] - a[4] * a[4] / nn;
        const double chh = a[8] - a[5] * a[5] / nn;
        const double cll = a[9] - a[6] * a[6] / nn;
        const double num = a[13]
            - (a[4] * a[12] + a[5] * a[11] + a[6] * a[10]) / nn
            + 2.0 * a[4] * a[5] * a[6] / (nn * nn);
        sc[t] = num / sqrt(cvv * chh * cll);
        sd[t] = 2.0 * (a[2] + 1.0) / (a[1] + a[3] + 1.0);
        sb[t] = a[0];
    }
    __syncthreads();
    if (t == 0) {
        double bces = 0.0, ds = 0.0, cs = 0.0;
#pragma unroll
        for (int i = 0; i < NSAMP; ++i) { bces += sb[i]; ds += sd[i]; cs += sc[i]; }
        const double bceloss = -bces / ((double)NSAMP * HW * HW);
        out[0] = (float)(0.2 * bceloss + 0.3 * (1.0 - ds / NSAMP) + 0.5 * (-cs / NSAMP));
    }
}

extern "C" void kernel_launch(void* const* d_in, const int* in_sizes, int n_in,
                              void* d_out, int out_size, void* d_ws, size_t ws_size,
                              hipStream_t stream) {
    const float* logits = (const float*)d_in[0];
    const float* labels = (const float*)d_in[1];
    const float* v_att  = (const float*)d_in[2];
    const float* h_att  = (const float*)d_in[3];
    float* out  = (float*)d_out;
    float* part = (float*)d_ws;   // NACC * NBLOCKS floats = 28 KB

    covloss_main<<<NBLOCKS, 256, 0, stream>>>(logits, labels, v_att, h_att, part);
    covloss_finalize<<<1, 256, 0, stream>>>(part, out);
}